// Round 9
// baseline (437.541 us; speedup 1.0000x reference)
//
#include <hip/hip_runtime.h>
#include <hip/hip_bf16.h>
#include <stdint.h>
#include <math.h>

typedef __attribute__((ext_vector_type(8))) short bf16x8;
typedef __attribute__((ext_vector_type(4))) float f32x4;

#define GLD16(gp, lp) __builtin_amdgcn_global_load_lds( \
    (const __attribute__((address_space(1))) void*)(gp), \
    (__attribute__((address_space(3))) void*)(lp), 16, 0, 0)

// ---------------- convert f32 -> bf16 (x4 vectorized) ----------------
struct bf16_4 { __hip_bfloat16 x, y, z, w; };

__global__ __launch_bounds__(256) void k_conv(const float* __restrict__ in,
                                              __hip_bfloat16* __restrict__ out, int n4)
{
    int i = blockIdx.x * 256 + threadIdx.x;
    if (i >= n4) return;
    float4 v = ((const float4*)in)[i];
    bf16_4 o = { __float2bfloat16(v.x), __float2bfloat16(v.y),
                 __float2bfloat16(v.z), __float2bfloat16(v.w) };
    ((bf16_4*)out)[i] = o;
}

// ------------- transpose+convert: in[R][C] f32 -> out[C][R] bf16 -------------
__global__ __launch_bounds__(256) void k_tconv(const float* __restrict__ in,
                                               __hip_bfloat16* __restrict__ out,
                                               int R, int C)
{
    __shared__ float tile[32][33];
    int c0 = blockIdx.x * 32, r0 = blockIdx.y * 32;
    int tc = threadIdx.x & 31, tr = threadIdx.x >> 5;  // tr in 0..7
#pragma unroll
    for (int i = 0; i < 4; i++)
        tile[tr + i * 8][tc] = in[(size_t)(r0 + tr + i * 8) * C + c0 + tc];
    __syncthreads();
#pragma unroll
    for (int i = 0; i < 4; i++) {
        int r = tr + i * 8;
        out[(size_t)(c0 + r) * R + r0 + tc] = __float2bfloat16(tile[tc][r]);
    }
}

// ------------- bf16 per-head transpose: vin[32][2048][64] -> vout[32][64][2048] -------------
__global__ __launch_bounds__(256) void k_vtrans(const __hip_bfloat16* __restrict__ vin,
                                                __hip_bfloat16* __restrict__ vout)
{
    __shared__ __hip_bfloat16 t[64 * 80];
    const int kt = blockIdx.x, bh = blockIdx.y;
    const int tid = threadIdx.x;
    const size_t ib = (size_t)bh * 131072;
#pragma unroll
    for (int i = 0; i < 2; i++) {
        int c = i * 256 + tid;
        int kv = c >> 3, d0 = (c & 7) * 8;
        bf16x8 vv = *(const bf16x8*)(vin + ib + (size_t)(kt * 64 + kv) * 64 + d0);
#pragma unroll
        for (int j = 0; j < 8; j++)
            t[(d0 + j) * 80 + kv] = ((const __hip_bfloat16*)&vv)[j];
    }
    __syncthreads();
#pragma unroll
    for (int i = 0; i < 2; i++) {
        int c = i * 256 + tid;
        int d = c >> 3, kv0 = (c & 7) * 8;
        *(bf16x8*)(vout + ib + (size_t)d * 2048 + kt * 64 + kv0) =
            *(const bf16x8*)(t + d * 80 + kv0);
    }
}

// ============ big-tile double-buffered GEMM: C = A @ Bt^T + bias ============
template <int BM, int BN, int TM, int TN, int EPI>
__global__ __launch_bounds__(TM * TN * 64, 2) void k_gemm2(
    const __hip_bfloat16* __restrict__ A,
    const __hip_bfloat16* __restrict__ Bt,
    const float* __restrict__ bias,
    float* __restrict__ outf,
    __hip_bfloat16* __restrict__ outb,
    int M, int N, int K)
{
    constexpr int THREADS = TM * TN * 64;
    constexpr int NMI = BM / TM / 16;
    constexpr int NNI = BN / TN / 16;
    constexpr int ACH = BM * 8 / THREADS;
    constexpr int BCH = BN * 8 / THREADS;

    __shared__ __hip_bfloat16 As[2][BM * 64];
    __shared__ __hip_bfloat16 Bs[2][BN * 64];

    const int tid  = threadIdx.x;
    const int lane = tid & 63, wid = tid >> 6;
    const int wm = wid / TN, wn = wid % TN;
    const int lr = lane & 15, lg = lane >> 4;
    const int m0 = blockIdx.y * BM, n0 = blockIdx.x * BN;
    const int NT = K >> 6;

    f32x4 acc[NMI][NNI] = {};

    auto stage = [&](int bb, int t) {
#pragma unroll
        for (int i = 0; i < ACH; i++) {
            int c = i * THREADS + tid;
            int r = c >> 3, sl = c & 7;
            GLD16(A + (size_t)(m0 + r) * K + t * 64 + ((sl ^ (r & 7)) * 8),
                  &As[bb][(size_t)(i * THREADS + wid * 64) * 8]);
        }
#pragma unroll
        for (int i = 0; i < BCH; i++) {
            int c = i * THREADS + tid;
            int r = c >> 3, sl = c & 7;
            GLD16(Bt + (size_t)(n0 + r) * K + t * 64 + ((sl ^ (r & 7)) * 8),
                  &Bs[bb][(size_t)(i * THREADS + wid * 64) * 8]);
        }
    };

    stage(0, 0);
    __syncthreads();
    int cur = 0;
#pragma unroll 1
    for (int t = 0; t < NT; ++t) {
        if (t + 1 < NT) stage(cur ^ 1, t + 1);
        __builtin_amdgcn_s_setprio(1);
        bf16x8 bfr[NNI][2];
#pragma unroll
        for (int ni = 0; ni < NNI; ni++) {
            int r = wn * (BN / TN) + ni * 16 + lr;
#pragma unroll
            for (int kk = 0; kk < 2; kk++)
                bfr[ni][kk] = *(const bf16x8*)(&Bs[cur][r * 64 + (((kk * 4 + lg) ^ (r & 7)) * 8)]);
        }
#pragma unroll
        for (int mi = 0; mi < NMI; mi++) {
            int r = wm * (BM / TM) + mi * 16 + lr;
            bf16x8 a0 = *(const bf16x8*)(&As[cur][r * 64 + (((0 + lg) ^ (r & 7)) * 8)]);
            bf16x8 a1 = *(const bf16x8*)(&As[cur][r * 64 + (((4 + lg) ^ (r & 7)) * 8)]);
#pragma unroll
            for (int ni = 0; ni < NNI; ni++) {
                acc[mi][ni] = __builtin_amdgcn_mfma_f32_16x16x32_bf16(a0, bfr[ni][0], acc[mi][ni], 0, 0, 0);
                acc[mi][ni] = __builtin_amdgcn_mfma_f32_16x16x32_bf16(a1, bfr[ni][1], acc[mi][ni], 0, 0, 0);
            }
        }
        __builtin_amdgcn_s_setprio(0);
        __syncthreads();
        cur ^= 1;
    }

#pragma unroll
    for (int mi = 0; mi < NMI; mi++) {
#pragma unroll
        for (int ni = 0; ni < NNI; ni++) {
#pragma unroll
            for (int j = 0; j < 4; j++) {
                int mg = m0 + wm * (BM / TM) + mi * 16 + 4 * lg + j;
                int ng = n0 + wn * (BN / TN) + ni * 16 + lr;
                float val = acc[mi][ni][j] + bias[ng];
                if (EPI == 0) {
                    int part = ng >> 10;
                    int h    = (ng >> 6) & 15;
                    int dd   = ng & 63;
                    int b    = mg >> 11;
                    int s    = mg & 2047;
                    size_t idx = ((size_t)part << 22) + ((((size_t)b * 16 + h) * 2048 + s) << 6) + dd;
                    outf[idx] = val;
                    outb[idx] = __float2bfloat16(val);
                } else {
                    outf[(size_t)mg * N + ng] = val;
                }
            }
        }
    }
}

// ---------------- flash attention v5: v2 structure + T14 async-STAGE split ----------------
// QB=64 (4 waves x 16 rows), KVB=128, paired q-tiles (31-bx, bx): 17 steps/block.
// Reg-staged K/V: global loads for tile kt+1 issued BEFORE compute of tile kt
// (HBM latency hides under QK^T+softmax+PV); ds_write to XOR-swizzled dest,
// fragment reads unchanged (<=2-way). 3 blocks/CU.
__global__ __launch_bounds__(256, 3) void k_attn5(const __hip_bfloat16* __restrict__ qkv,
                                                  const __hip_bfloat16* __restrict__ vT,
                                                  const int* __restrict__ amask,
                                                  __hip_bfloat16* __restrict__ ctx)
{
    const int bx = blockIdx.x;      // 0..15
    const int bh = blockIdx.y;      // 0..31
    const int b = bh >> 4, h = bh & 15;
    const int tid = threadIdx.x;
    const int lane = tid & 63, w = tid >> 6;
    const int lr = lane & 15, lg = lane >> 4;
    const size_t hb = (size_t)bh * (2048 * 64);
    const __hip_bfloat16* qg = qkv + hb;
    const __hip_bfloat16* kg = qkv + ((size_t)1 << 22) + hb;
    const __hip_bfloat16* vt = vT + (size_t)bh * (64 * 2048);

    __shared__ __hip_bfloat16 Ks[128 * 64];     // [kv][d], swz slot^(r&7)
    __shared__ __hip_bfloat16 Vs[64 * 128];     // [d][kv], swz slot^(r&15)
    __shared__ __hip_bfloat16 Ps[4][16 * 128];  // per-wave P, swz slot^row
    __shared__ float maskadd[128];

    const float SC = 0.18033688011112042f;      // 0.125 * log2(e)

#pragma unroll 1
    for (int pass = 0; pass < 2; ++pass) {
        const int qt = pass ? bx : (31 - bx);
        const int q0 = qt * 64;
        const int nkt = (64 * qt + 191) >> 7;   // kv tiles covering causal span

        bf16x8 qf[2];
#pragma unroll
        for (int kk = 0; kk < 2; kk++)
            qf[kk] = *(const bf16x8*)(qg + (size_t)(q0 + w * 16 + lr) * 64 + kk * 32 + 8 * lg);

        f32x4 of[4] = {};
        float m_run[4], l_run[4];
#pragma unroll
        for (int j = 0; j < 4; j++) { m_run[j] = -1e30f; l_run[j] = 0.f; }
        const int wrow0 = q0 + w * 16;
        const int rowg = wrow0 + 4 * lg;

        // prologue: issue tile-0 loads into regs (linear/coalesced global reads)
        bf16x8 kreg[4], vreg[4];
#pragma unroll
        for (int i = 0; i < 4; i++) {
            int c = i * 256 + tid;
            kreg[i] = *(const bf16x8*)(kg + (size_t)(c >> 3) * 64 + (c & 7) * 8);
            vreg[i] = *(const bf16x8*)(vt + (size_t)(c >> 4) * 2048 + (c & 15) * 8);
        }

#pragma unroll 1
        for (int kt = 0; kt < nkt; ++kt) {
            const int k0 = kt * 128;
            __syncthreads();               // all waves done reading previous LDS tile
            // publish staged regs -> LDS (swizzled dest; compiler waits vmcnt as needed)
#pragma unroll
            for (int i = 0; i < 4; i++) {
                int c = i * 256 + tid;
                int kr = c >> 3, ksl = c & 7;
                *(bf16x8*)(Ks + (size_t)kr * 64 + ((ksl ^ (kr & 7)) * 8)) = kreg[i];
                int vr = c >> 4, vsl = c & 15;
                *(bf16x8*)(Vs + (size_t)vr * 128 + ((vsl ^ (vr & 15)) * 8)) = vreg[i];
            }
            if (tid < 128) maskadd[tid] = amask[b * 2048 + k0 + tid] ? 0.f : -1e30f;
            // issue NEXT tile's loads now — latency hides under compute below
            bf16x8 kn[4], vn[4];
            if (kt + 1 < nkt) {
                const int k1 = k0 + 128;
#pragma unroll
                for (int i = 0; i < 4; i++) {
                    int c = i * 256 + tid;
                    kn[i] = *(const bf16x8*)(kg + (size_t)(k1 + (c >> 3)) * 64 + (c & 7) * 8);
                    vn[i] = *(const bf16x8*)(vt + (size_t)(c >> 4) * 2048 + k1 + (c & 15) * 8);
                }
            }
            __syncthreads();               // LDS published

            // S = Q K^T : 16 MFMA
            __builtin_amdgcn_s_setprio(1);
            f32x4 sa[8] = {};
#pragma unroll
            for (int ni = 0; ni < 8; ni++) {
                int r = ni * 16 + lr;
#pragma unroll
                for (int kk = 0; kk < 2; kk++) {
                    bf16x8 kf = *(const bf16x8*)(Ks + (size_t)r * 64 + (((kk * 4 + lg) ^ (r & 7)) * 8));
                    sa[ni] = __builtin_amdgcn_mfma_f32_16x16x32_bf16(qf[kk], kf, sa[ni], 0, 0, 0);
                }
            }
            __builtin_amdgcn_s_setprio(0);
            // scale (log2 domain) + pad mask; causal compare only where tile crosses diagonal
            if (k0 + 127 <= wrow0) {
#pragma unroll
                for (int ni = 0; ni < 8; ni++) {
                    float ma = maskadd[ni * 16 + lr];
#pragma unroll
                    for (int j = 0; j < 4; j++)
                        sa[ni][j] = fmaf(sa[ni][j], SC, ma);
                }
            } else {
#pragma unroll
                for (int ni = 0; ni < 8; ni++) {
                    int colg = k0 + ni * 16 + lr;
                    float ma = maskadd[ni * 16 + lr];
#pragma unroll
                    for (int j = 0; j < 4; j++) {
                        float val = fmaf(sa[ni][j], SC, ma);
                        if (colg > rowg + j) val = -1e30f;
                        sa[ni][j] = val;
                    }
                }
            }
            // online softmax (base-2), rows in 16-lane groups
            float mnew[4], corr[4];
#pragma unroll
            for (int j = 0; j < 4; j++) {
                float t = fmaxf(fmaxf(fmaxf(sa[0][j], sa[1][j]), fmaxf(sa[2][j], sa[3][j])),
                                fmaxf(fmaxf(sa[4][j], sa[5][j]), fmaxf(sa[6][j], sa[7][j])));
                t = fmaxf(t, __shfl_xor(t, 1));
                t = fmaxf(t, __shfl_xor(t, 2));
                t = fmaxf(t, __shfl_xor(t, 4));
                t = fmaxf(t, __shfl_xor(t, 8));
                mnew[j] = fmaxf(m_run[j], t);
                corr[j] = exp2f(m_run[j] - mnew[j]);
                m_run[j] = mnew[j];
            }
            float tsum[4] = {0.f, 0.f, 0.f, 0.f};
#pragma unroll
            for (int ni = 0; ni < 8; ni++)
#pragma unroll
                for (int j = 0; j < 4; j++) {
                    float p = exp2f(sa[ni][j] - mnew[j]);
                    sa[ni][j] = p;
                    tsum[j] += p;
                }
#pragma unroll
            for (int j = 0; j < 4; j++) {
                float t = tsum[j];
                t += __shfl_xor(t, 1);
                t += __shfl_xor(t, 2);
                t += __shfl_xor(t, 4);
                t += __shfl_xor(t, 8);
                l_run[j] = l_run[j] * corr[j] + t;
#pragma unroll
                for (int nd = 0; nd < 4; nd++) of[nd][j] *= corr[j];
            }
            // P -> per-wave LDS (bf16, XOR-swizzled), re-fragment for PV
#pragma unroll
            for (int ni = 0; ni < 8; ni++)
#pragma unroll
                for (int j = 0; j < 4; j++) {
                    int row = 4 * lg + j, col = ni * 16 + lr;
                    Ps[w][row * 128 + (((col >> 3) ^ row) * 8) + (col & 7)] =
                        __float2bfloat16(sa[ni][j]);
                }
            asm volatile("s_waitcnt lgkmcnt(0)" ::: "memory");
            __builtin_amdgcn_sched_barrier(0);
            // O += P @ V : 16 MFMA
            __builtin_amdgcn_s_setprio(1);
#pragma unroll
            for (int kk = 0; kk < 4; kk++) {
                bf16x8 pf = *(const bf16x8*)(&Ps[w][lr * 128 + (((kk * 4 + lg) ^ lr) * 8)]);
#pragma unroll
                for (int nd = 0; nd < 4; nd++) {
                    int r = nd * 16 + lr;
                    bf16x8 vf = *(const bf16x8*)(Vs + (size_t)r * 128 + (((kk * 4 + lg) ^ (r & 15)) * 8));
                    of[nd] = __builtin_amdgcn_mfma_f32_16x16x32_bf16(pf, vf, of[nd], 0, 0, 0);
                }
            }
            __builtin_amdgcn_s_setprio(0);
            // rotate staging regs (static indices)
#pragma unroll
            for (int i = 0; i < 4; i++) { kreg[i] = kn[i]; vreg[i] = vn[i]; }
        }
        // epilogue: ctx[b][s][h*64+d] = O / l
#pragma unroll
        for (int j = 0; j < 4; j++) {
            float inv = 1.f / l_run[j];
            int s = rowg + j;
            size_t base = ((size_t)b * 2048 + s) * 1024 + h * 64;
#pragma unroll
            for (int nd = 0; nd < 4; nd++)
                ctx[base + nd * 16 + lr] = __float2bfloat16(of[nd][j] * inv);
        }
    }
}

extern "C" void kernel_launch(void* const* d_in, const int* in_sizes, int n_in,
                              void* d_out, int out_size, void* d_ws, size_t ws_size,
                              hipStream_t stream)
{
    const float* x    = (const float*)d_in[0];
    const int*   am   = (const int*)d_in[1];
    const float* Wqkv = (const float*)d_in[2];
    const float* bqkv = (const float*)d_in[3];
    const float* Wout = (const float*)d_in[4];
    const float* bout = (const float*)d_in[5];
    float* out = (float*)d_out;

    char* ws = (char*)d_ws;
    __hip_bfloat16* x_bf   = (__hip_bfloat16*)(ws);                      //  8 MB (reused as vT)
    __hip_bfloat16* Wqkv_t = (__hip_bfloat16*)(ws + ((size_t)8 << 20));  //  6 MB [3072][1024]
    __hip_bfloat16* Wout_t = (__hip_bfloat16*)(ws + ((size_t)14 << 20)); //  2 MB [1024][1024]
    __hip_bfloat16* qkv_bf = (__hip_bfloat16*)(ws + ((size_t)16 << 20)); // 24 MB [3][32][2048][64]
    __hip_bfloat16* ctx_bf = (__hip_bfloat16*)(ws + ((size_t)40 << 20)); //  8 MB [4096][1024]
    __hip_bfloat16* vT     = x_bf;

    k_conv<<<4096, 256, 0, stream>>>(x, x_bf, 1048576);
    k_tconv<<<dim3(96, 32), 256, 0, stream>>>(Wqkv, Wqkv_t, 1024, 3072);
    k_tconv<<<dim3(32, 32), 256, 0, stream>>>(Wout, Wout_t, 1024, 1024);
    // QKV GEMM: 256x192 tile, 8 waves, grid 16x16 = 256 blocks (1/CU)
    k_gemm2<256, 192, 2, 4, 0><<<dim3(16, 16), 512, 0, stream>>>(
        x_bf, Wqkv_t, bqkv, out + ((size_t)1 << 22), qkv_bf, 4096, 3072, 1024);
    // V^T per head (x_bf dead now; reuse as vT)
    k_vtrans<<<dim3(32, 32), 256, 0, stream>>>(qkv_bf + ((size_t)2 << 22), vT);
    // attention: 16 paired q-tiles x 32 (b,h), 4 waves, reg-staged prefetch
    k_attn5<<<dim3(16, 32), 256, 0, stream>>>(qkv_bf, vT, am, ctx_bf);
    // out-proj GEMM: 128x128 tile, 4 waves, grid 8x32 = 256 blocks (2/CU)
    k_gemm2<128, 128, 2, 2, 1><<<dim3(8, 32), 256, 0, stream>>>(
        ctx_bf, Wout_t, bout, out, nullptr, 4096, 1024, 1024);
}

// Round 10
// 236.869 us; speedup vs baseline: 1.8472x; 1.8472x over previous
//
#include <hip/hip_runtime.h>
#include <hip/hip_bf16.h>
#include <stdint.h>

typedef __attribute__((ext_vector_type(8))) short bf16x8;
typedef __attribute__((ext_vector_type(4))) float f32x4;

#define GLD16(gp, lp) __builtin_amdgcn_global_load_lds( \
    (const __attribute__((address_space(1))) void*)(gp), \
    (__attribute__((address_space(3))) void*)(lp), 16, 0, 0)

// ---------------- convert f32 -> bf16 (x4 vectorized) ----------------
struct bf16_4 { __hip_bfloat16 x, y, z, w; };

__global__ __launch_bounds__(256) void k_conv(const float* __restrict__ in,
                                              __hip_bfloat16* __restrict__ out, int n4)
{
    int i = blockIdx.x * 256 + threadIdx.x;
    if (i >= n4) return;
    float4 v = ((const float4*)in)[i];
    bf16_4 o = { __float2bfloat16(v.x), __float2bfloat16(v.y),
                 __float2bfloat16(v.z), __float2bfloat16(v.w) };
    ((bf16_4*)out)[i] = o;
}

// ------------- transpose+convert: in[R][C] f32 -> out[C][R] bf16 -------------
__global__ __launch_bounds__(256) void k_tconv(const float* __restrict__ in,
                                               __hip_bfloat16* __restrict__ out,
                                               int R, int C)
{
    __shared__ float tile[32][33];
    int c0 = blockIdx.x * 32, r0 = blockIdx.y * 32;
    int tc = threadIdx.x & 31, tr = threadIdx.x >> 5;  // tr in 0..7
#pragma unroll
    for (int i = 0; i < 4; i++)
        tile[tr + i * 8][tc] = in[(size_t)(r0 + tr + i * 8) * C + c0 + tc];
    __syncthreads();
#pragma unroll
    for (int i = 0; i < 4; i++) {
        int r = tr + i * 8;
        out[(size_t)(c0 + r) * R + r0 + tc] = __float2bfloat16(tile[tc][r]);
    }
}

// ------------- bf16 per-head transpose: vin[32][2048][64] -> vout[32][64][2048] -------------
__global__ __launch_bounds__(256) void k_vtrans(const __hip_bfloat16* __restrict__ vin,
                                                __hip_bfloat16* __restrict__ vout)
{
    __shared__ __hip_bfloat16 t[64 * 80];
    const int kt = blockIdx.x, bh = blockIdx.y;
    const int tid = threadIdx.x;
    const size_t ib = (size_t)bh * 131072;
#pragma unroll
    for (int i = 0; i < 2; i++) {
        int c = i * 256 + tid;
        int kv = c >> 3, d0 = (c & 7) * 8;
        bf16x8 vv = *(const bf16x8*)(vin + ib + (size_t)(kt * 64 + kv) * 64 + d0);
#pragma unroll
        for (int j = 0; j < 8; j++)
            t[(d0 + j) * 80 + kv] = ((const __hip_bfloat16*)&vv)[j];
    }
    __syncthreads();
#pragma unroll
    for (int i = 0; i < 2; i++) {
        int c = i * 256 + tid;
        int d = c >> 3, kv0 = (c & 7) * 8;
        *(bf16x8*)(vout + ib + (size_t)d * 2048 + kt * 64 + kv0) =
            *(const bf16x8*)(t + d * 80 + kv0);
    }
}

// ============ big-tile double-buffered GEMM: C = A @ Bt^T + bias ============
// A: [M][K] bf16, Bt: [N][K] bf16. BK=64, dbuf LDS, T2 XOR-swizzle (slot^(row&7)).
// Per K-tile: issue next-tile global_load_lds, compute current, one barrier
// (its vmcnt(0) drain lands after a full MFMA block -> latency hidden when
// >=2 blocks/CU are resident). EPI=0: QKV scatter; EPI=1: row-major f32.
template <int BM, int BN, int TM, int TN, int EPI>
__global__ __launch_bounds__(TM * TN * 64, 2) void k_gemm2(
    const __hip_bfloat16* __restrict__ A,
    const __hip_bfloat16* __restrict__ Bt,
    const float* __restrict__ bias,
    float* __restrict__ outf,
    __hip_bfloat16* __restrict__ outb,
    int M, int N, int K)
{
    constexpr int THREADS = TM * TN * 64;
    constexpr int NMI = BM / TM / 16;
    constexpr int NNI = BN / TN / 16;
    constexpr int ACH = BM * 8 / THREADS;
    constexpr int BCH = BN * 8 / THREADS;

    __shared__ __hip_bfloat16 As[2][BM * 64];
    __shared__ __hip_bfloat16 Bs[2][BN * 64];

    const int tid  = threadIdx.x;
    const int lane = tid & 63, wid = tid >> 6;
    const int wm = wid / TN, wn = wid % TN;
    const int lr = lane & 15, lg = lane >> 4;
    const int m0 = blockIdx.y * BM, n0 = blockIdx.x * BN;
    const int NT = K >> 6;

    f32x4 acc[NMI][NNI] = {};

    auto stage = [&](int bb, int t) {
#pragma unroll
        for (int i = 0; i < ACH; i++) {
            int c = i * THREADS + tid;
            int r = c >> 3, sl = c & 7;
            GLD16(A + (size_t)(m0 + r) * K + t * 64 + ((sl ^ (r & 7)) * 8),
                  &As[bb][(size_t)(i * THREADS + wid * 64) * 8]);
        }
#pragma unroll
        for (int i = 0; i < BCH; i++) {
            int c = i * THREADS + tid;
            int r = c >> 3, sl = c & 7;
            GLD16(Bt + (size_t)(n0 + r) * K + t * 64 + ((sl ^ (r & 7)) * 8),
                  &Bs[bb][(size_t)(i * THREADS + wid * 64) * 8]);
        }
    };

    stage(0, 0);
    __syncthreads();
    int cur = 0;
#pragma unroll 1
    for (int t = 0; t < NT; ++t) {
        if (t + 1 < NT) stage(cur ^ 1, t + 1);
        __builtin_amdgcn_s_setprio(1);
        bf16x8 bfr[NNI][2];
#pragma unroll
        for (int ni = 0; ni < NNI; ni++) {
            int r = wn * (BN / TN) + ni * 16 + lr;
#pragma unroll
            for (int kk = 0; kk < 2; kk++)
                bfr[ni][kk] = *(const bf16x8*)(&Bs[cur][r * 64 + (((kk * 4 + lg) ^ (r & 7)) * 8)]);
        }
#pragma unroll
        for (int mi = 0; mi < NMI; mi++) {
            int r = wm * (BM / TM) + mi * 16 + lr;
            bf16x8 a0 = *(const bf16x8*)(&As[cur][r * 64 + (((0 + lg) ^ (r & 7)) * 8)]);
            bf16x8 a1 = *(const bf16x8*)(&As[cur][r * 64 + (((4 + lg) ^ (r & 7)) * 8)]);
#pragma unroll
            for (int ni = 0; ni < NNI; ni++) {
                acc[mi][ni] = __builtin_amdgcn_mfma_f32_16x16x32_bf16(a0, bfr[ni][0], acc[mi][ni], 0, 0, 0);
                acc[mi][ni] = __builtin_amdgcn_mfma_f32_16x16x32_bf16(a1, bfr[ni][1], acc[mi][ni], 0, 0, 0);
            }
        }
        __builtin_amdgcn_s_setprio(0);
        __syncthreads();
        cur ^= 1;
    }

#pragma unroll
    for (int mi = 0; mi < NMI; mi++) {
#pragma unroll
        for (int ni = 0; ni < NNI; ni++) {
#pragma unroll
            for (int j = 0; j < 4; j++) {
                int mg = m0 + wm * (BM / TM) + mi * 16 + 4 * lg + j;
                int ng = n0 + wn * (BN / TN) + ni * 16 + lr;
                float val = acc[mi][ni][j] + bias[ng];
                if (EPI == 0) {
                    int part = ng >> 10;
                    int h    = (ng >> 6) & 15;
                    int dd   = ng & 63;
                    int b    = mg >> 11;
                    int s    = mg & 2047;
                    size_t idx = ((size_t)part << 22) + ((((size_t)b * 16 + h) * 2048 + s) << 6) + dd;
                    outf[idx] = val;
                    outb[idx] = __float2bfloat16(val);
                } else {
                    outf[(size_t)mg * N + ng] = val;
                }
            }
        }
    }
}

// ---------------- flash-style causal attention v2 (exact R3 anchor, 74 us) ----------------
__global__ __launch_bounds__(256, 3) void k_attn2(const __hip_bfloat16* __restrict__ qkv,
                                                  const __hip_bfloat16* __restrict__ vT,
                                                  const int* __restrict__ amask,
                                                  __hip_bfloat16* __restrict__ ctx)
{
    const int bx = blockIdx.x;      // 0..15
    const int bh = blockIdx.y;      // 0..31
    const int b = bh >> 4, h = bh & 15;
    const int tid = threadIdx.x;
    const int lane = tid & 63, w = tid >> 6;
    const int lr = lane & 15, lg = lane >> 4;
    const size_t hb = (size_t)bh * (2048 * 64);
    const __hip_bfloat16* qg = qkv + hb;
    const __hip_bfloat16* kg = qkv + ((size_t)1 << 22) + hb;
    const __hip_bfloat16* vt = vT + (size_t)bh * (64 * 2048);

    __shared__ __hip_bfloat16 Ks[128 * 64];     // [kv][d], swz slot^(r&7)
    __shared__ __hip_bfloat16 Vs[64 * 128];     // [d][kv], swz slot^(r&15)
    __shared__ __hip_bfloat16 Ps[4][16 * 128];  // per-wave P, swz slot^row
    __shared__ float maskadd[128];

#pragma unroll 1
    for (int pass = 0; pass < 2; ++pass) {
        const int qt = pass ? bx : (31 - bx);
        const int q0 = qt * 64;
        const int nkt = (64 * qt + 191) >> 7;   // kv tiles covering causal span

        bf16x8 qf[2];
#pragma unroll
        for (int kk = 0; kk < 2; kk++)
            qf[kk] = *(const bf16x8*)(qg + (size_t)(q0 + w * 16 + lr) * 64 + kk * 32 + 8 * lg);

        f32x4 of[4] = {};
        float m_run[4], l_run[4];
#pragma unroll
        for (int j = 0; j < 4; j++) { m_run[j] = -1e30f; l_run[j] = 0.f; }
        const int rowg = q0 + w * 16 + 4 * lg;

#pragma unroll 1
        for (int kt = 0; kt < nkt; ++kt) {
            const int k0 = kt * 128;
            __syncthreads();
#pragma unroll
            for (int i = 0; i < 4; i++) {
                int c = i * 256 + tid;
                int r = c >> 3, sl = c & 7;
                GLD16(kg + (size_t)(k0 + r) * 64 + ((sl ^ (r & 7)) * 8),
                      Ks + (size_t)(i * 256 + w * 64) * 8);
            }
#pragma unroll
            for (int i = 0; i < 4; i++) {
                int c = i * 256 + tid;
                int r = c >> 4, sl = c & 15;
                GLD16(vt + (size_t)r * 2048 + k0 + ((sl ^ (r & 15)) * 8),
                      Vs + (size_t)(i * 256 + w * 64) * 8);
            }
            if (tid < 128) maskadd[tid] = amask[b * 2048 + k0 + tid] ? 0.f : -1e30f;
            __syncthreads();

            // S = Q K^T : 16 MFMA (8 ni x 2 kk)
            f32x4 sa[8] = {};
#pragma unroll
            for (int ni = 0; ni < 8; ni++) {
                int r = ni * 16 + lr;
#pragma unroll
                for (int kk = 0; kk < 2; kk++) {
                    bf16x8 kf = *(const bf16x8*)(Ks + (size_t)r * 64 + (((kk * 4 + lg) ^ (r & 7)) * 8));
                    sa[ni] = __builtin_amdgcn_mfma_f32_16x16x32_bf16(qf[kk], kf, sa[ni], 0, 0, 0);
                }
            }
#pragma unroll
            for (int ni = 0; ni < 8; ni++) {
                int colg = k0 + ni * 16 + lr;
                float ma = maskadd[ni * 16 + lr];
#pragma unroll
                for (int j = 0; j < 4; j++) {
                    float val = sa[ni][j] * 0.125f + ma;
                    if (colg > rowg + j) val = -1e30f;
                    sa[ni][j] = val;
                }
            }
            float mnew[4], corr[4];
#pragma unroll
            for (int j = 0; j < 4; j++) {
                float t = fmaxf(fmaxf(fmaxf(sa[0][j], sa[1][j]), fmaxf(sa[2][j], sa[3][j])),
                                fmaxf(fmaxf(sa[4][j], sa[5][j]), fmaxf(sa[6][j], sa[7][j])));
                t = fmaxf(t, __shfl_xor(t, 1));
                t = fmaxf(t, __shfl_xor(t, 2));
                t = fmaxf(t, __shfl_xor(t, 4));
                t = fmaxf(t, __shfl_xor(t, 8));
                mnew[j] = fmaxf(m_run[j], t);
                corr[j] = __expf(m_run[j] - mnew[j]);
                m_run[j] = mnew[j];
            }
            float tsum[4] = {0.f, 0.f, 0.f, 0.f};
#pragma unroll
            for (int ni = 0; ni < 8; ni++)
#pragma unroll
                for (int j = 0; j < 4; j++) {
                    float p = __expf(sa[ni][j] - mnew[j]);
                    sa[ni][j] = p;
                    tsum[j] += p;
                }
#pragma unroll
            for (int j = 0; j < 4; j++) {
                float t = tsum[j];
                t += __shfl_xor(t, 1);
                t += __shfl_xor(t, 2);
                t += __shfl_xor(t, 4);
                t += __shfl_xor(t, 8);
                l_run[j] = l_run[j] * corr[j] + t;
#pragma unroll
                for (int nd = 0; nd < 4; nd++) of[nd][j] *= corr[j];
            }
#pragma unroll
            for (int ni = 0; ni < 8; ni++)
#pragma unroll
                for (int j = 0; j < 4; j++) {
                    int row = 4 * lg + j, col = ni * 16 + lr;
                    Ps[w][row * 128 + (((col >> 3) ^ row) * 8) + (col & 7)] =
                        __float2bfloat16(sa[ni][j]);
                }
            asm volatile("s_waitcnt lgkmcnt(0)" ::: "memory");
            __builtin_amdgcn_sched_barrier(0);
#pragma unroll
            for (int kk = 0; kk < 4; kk++) {
                bf16x8 pf = *(const bf16x8*)(&Ps[w][lr * 128 + (((kk * 4 + lg) ^ lr) * 8)]);
#pragma unroll
                for (int nd = 0; nd < 4; nd++) {
                    int r = nd * 16 + lr;
                    bf16x8 vf = *(const bf16x8*)(Vs + (size_t)r * 128 + (((kk * 4 + lg) ^ (r & 15)) * 8));
                    of[nd] = __builtin_amdgcn_mfma_f32_16x16x32_bf16(pf, vf, of[nd], 0, 0, 0);
                }
            }
        }
#pragma unroll
        for (int j = 0; j < 4; j++) {
            float inv = 1.f / l_run[j];
            int s = rowg + j;
            size_t base = ((size_t)b * 2048 + s) * 1024 + h * 64;
#pragma unroll
            for (int nd = 0; nd < 4; nd++)
                ctx[base + nd * 16 + lr] = __float2bfloat16(of[nd][j] * inv);
        }
    }
}

extern "C" void kernel_launch(void* const* d_in, const int* in_sizes, int n_in,
                              void* d_out, int out_size, void* d_ws, size_t ws_size,
                              hipStream_t stream)
{
    const float* x    = (const float*)d_in[0];
    const int*   am   = (const int*)d_in[1];
    const float* Wqkv = (const float*)d_in[2];
    const float* bqkv = (const float*)d_in[3];
    const float* Wout = (const float*)d_in[4];
    const float* bout = (const float*)d_in[5];
    float* out = (float*)d_out;

    char* ws = (char*)d_ws;
    __hip_bfloat16* x_bf   = (__hip_bfloat16*)(ws);                      //  8 MB (reused as vT)
    __hip_bfloat16* Wqkv_t = (__hip_bfloat16*)(ws + ((size_t)8 << 20));  //  6 MB [3072][1024]
    __hip_bfloat16* Wout_t = (__hip_bfloat16*)(ws + ((size_t)14 << 20)); //  2 MB [1024][1024]
    __hip_bfloat16* qkv_bf = (__hip_bfloat16*)(ws + ((size_t)16 << 20)); // 24 MB [3][32][2048][64]
    __hip_bfloat16* ctx_bf = (__hip_bfloat16*)(ws + ((size_t)40 << 20)); //  8 MB [4096][1024]
    __hip_bfloat16* vT     = x_bf;

    k_conv<<<4096, 256, 0, stream>>>(x, x_bf, 1048576);
    k_tconv<<<dim3(96, 32), 256, 0, stream>>>(Wqkv, Wqkv_t, 1024, 3072);
    k_tconv<<<dim3(32, 32), 256, 0, stream>>>(Wout, Wout_t, 1024, 1024);
    // QKV GEMM: 128x128 tile, 4 waves, grid 24x32 = 768 blocks (2/CU resident)
    k_gemm2<128, 128, 2, 2, 0><<<dim3(24, 32), 256, 0, stream>>>(
        x_bf, Wqkv_t, bqkv, out + ((size_t)1 << 22), qkv_bf, 4096, 3072, 1024);
    // V^T per head (x_bf dead now; reuse as vT)
    k_vtrans<<<dim3(32, 32), 256, 0, stream>>>(qkv_bf + ((size_t)2 << 22), vT);
    // attention: 16 paired q-tiles x 32 (b,h) — measured 74 us anchor
    k_attn2<<<dim3(16, 32), 256, 0, stream>>>(qkv_bf, vT, am, ctx_bf);
    // out-proj GEMM: 128x128 tile, 4 waves, grid 8x32 = 256 blocks (2/CU)
    k_gemm2<128, 128, 2, 2, 1><<<dim3(8, 32), 256, 0, stream>>>(
        ctx_bf, Wout_t, bout, out, nullptr, 4096, 1024, 1024);
}